// Round 3
// baseline (337.811 us; speedup 1.0000x reference)
//
#include <hip/hip_runtime.h>
#include <hip/hip_bf16.h>

typedef __bf16 bf16_t;
typedef __bf16 bf16x8 __attribute__((ext_vector_type(8)));
typedef float  f32x4  __attribute__((ext_vector_type(4)));

#define MFMA16(A,B,C) __builtin_amdgcn_mfma_f32_16x16x32_bf16(A,B,C,0,0,0)

constexpr int HIDc = 4544;   // 142 k-steps of 32
constexpr int NHc  = 71;
constexpr int NHPc = 80;
constexpr int HDc  = 64;
constexpr int Uc   = 32;
constexpr int Sc   = 2048;
constexpr int RQ   = 4672;   // (71+2)*64

// ---- workspace layout (bytes) ----
constexpr size_t OFF_FUSED = 0;           // [32][4672] f32 = 598016
constexpr size_t OFF_QHI   = 598016;      // [32][80][64] bf16
constexpr size_t OFF_QLO   = 925696;
constexpr size_t OFF_KCUR  = 1253376;     // [32][64] f32
constexpr size_t OFF_VCUR  = 1261568;
constexpr size_t OFF_MP    = 1269760;     // [32][NPB<=16][71] f32 (max 145408)
constexpr size_t OFF_LP    = 1415168;
constexpr size_t OFF_AHI   = 1560576;     // [32][4544] bf16
constexpr size_t OFF_ALO   = 1851392;
constexpr size_t OFF_OP    = 2142208;     // [32][NPB][71][64] f32

// fp32 -> bf16x8 load (32B aligned)
__device__ __forceinline__ bf16x8 ld8f(const float* base, long eidx) {
  const float* p = base + eidx;
  const f32x4 a = *(const f32x4*)p;
  const f32x4 b = *(const f32x4*)(p + 4);
  bf16x8 r;
  r[0]=(bf16_t)a[0]; r[1]=(bf16_t)a[1]; r[2]=(bf16_t)a[2]; r[3]=(bf16_t)a[3];
  r[4]=(bf16_t)b[0]; r[5]=(bf16_t)b[1]; r[6]=(bf16_t)b[2]; r[7]=(bf16_t)b[3];
  return r;
}

// async global -> LDS copies (lds dest = wave-uniform base + lane*size)
__device__ __forceinline__ void cp16(const float* g, float* l) {
  __builtin_amdgcn_global_load_lds((const __attribute__((address_space(1))) void*)g,
                                   (__attribute__((address_space(3))) void*)l, 16, 0, 0);
}
__device__ __forceinline__ void cp4(const float* g, float* l) {
  __builtin_amdgcn_global_load_lds((const __attribute__((address_space(1))) void*)g,
                                   (__attribute__((address_space(3))) void*)l, 4, 0, 0);
}

// ---------------- zero fused + d_out ----------------
__global__ __launch_bounds__(256) void k_zeros(float* fused, float* out) {
  const int i = blockIdx.x*256 + threadIdx.x;       // grid 1152 -> 294912
  if (i < Uc*RQ) fused[i] = 0.f;
  else           out[i - Uc*RQ] = 0.f;              // Uc*HIDc elements
}

// ---------------- Kernel 1: QKV GEMM, grid (73,8), atomic reduce ----------------
__global__ __launch_bounds__(256) void k_qkv(
    const float* __restrict__ hidden, const float* __restrict__ wqkv,
    float* __restrict__ fused)
{
  const int h = blockIdx.x, y = blockIdx.y;
  const int t = threadIdx.x;
  const int wave = t >> 6, lane = t & 63;
  const int c = lane & 15, q4 = lane >> 4;
  const int mt = wave & 1, kh = wave >> 1;
  const int ks0 = y*18;
  const int ksn = min(18, 142 - ks0);     // y=7 gets 16
  const int h1  = ksn >> 1;
  const int kbeg = ks0 + (kh ? h1 : 0);
  const int kend = ks0 + (kh ? ksn : h1);
  __shared__ float sD[Uc*HDc];

  const long abase = (long)(mt*16 + c)*HIDc + q4*8;
  const long bbase = ((long)h*64 + c)*HIDc + q4*8;
  f32x4 acc[4] = {};
#pragma unroll 3
  for (int ks = kbeg; ks < kend; ++ks) {
    const bf16x8 af = ld8f(hidden, abase + ks*32);
#pragma unroll
    for (int nf = 0; nf < 4; ++nf) {
      const bf16x8 bv = ld8f(wqkv, bbase + (long)nf*16*HIDc + ks*32);
      acc[nf] = MFMA16(af, bv, acc[nf]);
    }
  }
  if (kh == 0) {
#pragma unroll
    for (int r = 0; r < 4; ++r)
#pragma unroll
      for (int nf = 0; nf < 4; ++nf)
        sD[(mt*16 + q4*4 + r)*64 + nf*16 + c] = acc[nf][r];
  }
  __syncthreads();
  if (kh == 1) {
#pragma unroll
    for (int r = 0; r < 4; ++r)
#pragma unroll
      for (int nf = 0; nf < 4; ++nf)
        sD[(mt*16 + q4*4 + r)*64 + nf*16 + c] += acc[nf][r];
  }
  __syncthreads();
  for (int i = t; i < Uc*HDc; i += 256)
    atomicAdd(&fused[(long)(i >> 6)*RQ + h*64 + (i & 63)], sD[i]);
}

// ---------------- Kernel 2: rotary + hi/lo split, grid (80,4) ----------------
__global__ __launch_bounds__(256) void k_rotary(
    const float* __restrict__ fused,
    const float* __restrict__ cosp, const float* __restrict__ sinp,
    bf16_t* __restrict__ qhi, bf16_t* __restrict__ qlo,
    float* __restrict__ kcur, float* __restrict__ vcur)
{
  const int h  = blockIdx.x;    // 0..79
  const int u0 = blockIdx.y*8;  // 8 users per block
  const int t = threadIdx.x;
  __shared__ float sD[8*HDc];
  if (h < 73) {
    for (int i = t; i < 8*HDc; i += 256)
      sD[i] = fused[(long)(u0 + (i >> 6))*RQ + h*64 + (i & 63)];
    __syncthreads();
  }
  if (h >= NHc) {  // zero q pad rows 71..79
    for (int i = t; i < 8*HDc; i += 256) {
      const long idx = (((long)(u0 + (i >> 6)))*NHPc + h)*HDc + (i & 63);
      qhi[idx] = (bf16_t)0.f;  qlo[idx] = (bf16_t)0.f;
    }
  }
  if (h >= 73) return;
  for (int i = t; i < 8*HDc; i += 256) {
    const int u = u0 + (i >> 6), d = i & 63;
    const float x = sD[i];
    const float partner = sD[i ^ 32];     // flips d bit 5 only (same u)
    const float cs = cosp[u*HDc + d];
    const float sn = sinp[u*HDc + d];
    const float rh = (d < 32) ? -partner : partner;
    const float val = x*cs + rh*sn;
    if (h < NHc) {
      const long idx = ((long)u*NHPc + h)*HDc + d;
      const bf16_t hi = (bf16_t)val;
      qhi[idx] = hi;
      qlo[idx] = (bf16_t)(val - (float)hi);
    } else if (h == NHc) {
      kcur[u*HDc + d] = val;     // rotated shared K head
    } else {
      vcur[u*HDc + d] = x;       // V head: no rotary
    }
  }
}

// ---------------- Kernel 3: flash-decode partials, grid (32, NPB) ----------------
// Cooperative producer/consumer block: 8 waves (512 thr).
//   waves 0-4 : consumers, wave = head-tile ht (16 heads each, NHP=80)
//   wave 5    : K producer     wave 6 : V producer    wave 7 : mask producer
// 64-key PHASES: ring of 4 x 32-key slots = 2 phase-groups; phase p uses slots
// {2*(p&1), 2*(p&1)+1}. Producer per phase: B1 (next group free) -> issue 16
// cp16 into group (p+1)&1 -> s_waitcnt vmcnt(16) (phase p complete, p+1 in
// flight) -> B2 (phase p ready). Consumers: __syncthreads x2 then compute 64
// keys: 4 QK subtiles, ONE softmax over 16 slots, 2x PV. Fixed per-phase costs
// (shuffle trees, alpha broadcast, O-rescale, barriers) paid 8x not 16x.
constexpr int ATTN_SLOT_F   = 4096;
constexpr int ATTN_STAGE_F  = 4*ATTN_SLOT_F;            // 16384
constexpr int ATTN_SMEM_F   = ATTN_STAGE_F + 2048;      // 18432
constexpr int ATTN_SMEM_BYTES = ATTN_SMEM_F * 4;        // 73728 -> 2 blocks/CU

__global__ __launch_bounds__(512, 4) void k_attn(
    const float* __restrict__ kc, const float* __restrict__ vc,
    const float* __restrict__ masks,
    const bf16_t* __restrict__ qhi, const bf16_t* __restrict__ qlo,
    float* __restrict__ Mp, float* __restrict__ Lp, float* __restrict__ Op,
    const int NPB)
{
  extern __shared__ float smem[];
  const int u  = blockIdx.x;
  const int pb = blockIdx.y;
  const int tid = threadIdx.x;
  const int wave = __builtin_amdgcn_readfirstlane(tid >> 6);
  const int lane = tid & 63;
  const int c    = lane & 15;
  const int q4   = lane >> 4;
  const int pbpc = NPB >> 2;            // partial blocks per chunk
  const int keys_pb = 2048 / pbpc;      // keys per block
  const int ph_cnt  = keys_pb >> 6;     // 64-key phases
  const int chunk = pb / pbpc;
  const int inner = pb - chunk*pbpc;
  const int s_base = inner*keys_pb;
  const long kvbase = ((long)(chunk*Uc + u))*Sc;

  float* const stage = smem;
  float* const smask = smem + ATTN_STAGE_F;

  const int srow = lane >> 4;           // dest row within 4-row group
  const int scol = (lane & 15) << 2;    // dest d' base (f32 words)

  if (wave >= 5) {
    // ================= producer path =================
    if (wave == 7) {
      const int nmc = keys_pb >> 6;
      const float* gM = masks + kvbase + s_base;
      for (int i = 0; i < nmc; ++i)
        cp4(gM + i*64 + lane, smask + i*64);
      for (int p = 0; p < ph_cnt; ++p) {
        __builtin_amdgcn_s_barrier();                       // B1
        if (p == 0) asm volatile("s_waitcnt vmcnt(0)" ::: "memory");
        __builtin_amdgcn_s_barrier();                       // B2
      }
      return;
    }
    const float* gsrc = (wave == 5) ? kc : vc;
    const int vofs = (wave == 6) ? 2048 : 0;
    // prologue: phase 0 -> slots 0,1 (16 cp16)
#pragma unroll
    for (int sl = 0; sl < 2; ++sl) {
      const long tb = (kvbase + s_base + sl*32) * 64;
      float* dst = stage + sl*ATTN_SLOT_F + vofs;
#pragma unroll
      for (int i = 0; i < 8; ++i) {
        const int row = i*4 + srow;
        const int fz = ((row & 7) << 2) ^ (((row >> 3) & 1) << 4);
        cp16(gsrc + tb + row*64 + (scol ^ fz), dst + i*256);
      }
    }
    for (int p = 0; p < ph_cnt; ++p) {
      __builtin_amdgcn_s_barrier();                         // B1: group (p+1)&1 free
      if (p + 1 < ph_cnt) {
        const int g = ((p+1) & 1)*2;
#pragma unroll
        for (int sl = 0; sl < 2; ++sl) {
          const long tb = (kvbase + s_base + (long)(p+1)*64 + sl*32) * 64;
          float* dst = stage + (g + sl)*ATTN_SLOT_F + vofs;
#pragma unroll
          for (int i = 0; i < 8; ++i) {
            const int row = i*4 + srow;
            const int fz = ((row & 7) << 2) ^ (((row >> 3) & 1) << 4);
            cp16(gsrc + tb + row*64 + (scol ^ fz), dst + i*256);
          }
        }
        asm volatile("s_waitcnt vmcnt(16)" ::: "memory");   // phase p done
      } else {
        asm volatile("s_waitcnt vmcnt(0)" ::: "memory");
      }
      __builtin_amdgcn_s_barrier();                         // B2: phase p ready
    }
    return;
  }

  // ================= consumer path (wave = ht, 16 heads) =================
  const int ht = wave;
  bf16x8 qh[2], ql[2];
  {
    const bf16_t* qb  = qhi + ((long)u*NHPc + ht*16 + c)*HDc + q4*8;
    const bf16_t* qb2 = qlo + ((long)u*NHPc + ht*16 + c)*HDc + q4*8;
#pragma unroll
    for (int ks = 0; ks < 2; ++ks) {
      qh[ks] = *(const bf16x8*)(qb  + ks*32);
      ql[ks] = *(const bf16x8*)(qb2 + ks*32);
    }
  }

  float m_i = -INFINITY, l_i = 0.f;
  f32x4 Oa[4] = {};

  // K-row permutation so S^T C-layout == PV A-layout (zero shuffles):
  // A row m=c reads key(in 32-slot) = krow0 + mt2*4, krow0 = (c>>2)*8 + (c&3)
  const int krow0 = ((c >> 2) << 3) + (c & 3);

  for (int p = 0; p < ph_cnt; ++p) {
    __syncthreads();                                        // B1
    __syncthreads();                                        // B2: phase p ready
    const int g = (p & 1)*2;

    // ---- QK: 4 subtiles (h2, mt2); key = h2*32 + q4*8 + mt2*4 + r ----
    f32x4 S[2][2];
    __builtin_amdgcn_s_setprio(1);
#pragma unroll
    for (int h2 = 0; h2 < 2; ++h2) {
      float* const lK = stage + (g + h2)*ATTN_SLOT_F;
#pragma unroll
      for (int mt2 = 0; mt2 < 2; ++mt2) {
        const int row = krow0 + mt2*4;
        const int fz = ((row & 7) << 2) ^ (((row >> 3) & 1) << 4);
        bf16x8 k0, k1;
#pragma unroll
        for (int ks = 0; ks < 2; ++ks) {
          const int b0 = row*64 + ((ks*32 + q4*8) ^ fz);
          const int b1 = row*64 + ((ks*32 + q4*8 + 4) ^ fz);
          const f32x4 a = *(const f32x4*)(lK + b0);
          const f32x4 b = *(const f32x4*)(lK + b1);
          bf16x8 r;
          r[0]=(bf16_t)a[0]; r[1]=(bf16_t)a[1]; r[2]=(bf16_t)a[2]; r[3]=(bf16_t)a[3];
          r[4]=(bf16_t)b[0]; r[5]=(bf16_t)b[1]; r[6]=(bf16_t)b[2]; r[7]=(bf16_t)b[3];
          if (ks == 0) k0 = r; else k1 = r;
        }
        f32x4 s = {};
        s = MFMA16(k0, qh[0], s);
        s = MFMA16(k1, qh[1], s);
        s = MFMA16(k0, ql[0], s);
        s = MFMA16(k1, ql[1], s);
        S[h2][mt2] = s;
      }
    }
    __builtin_amdgcn_s_setprio(0);

    // scale + mask (broadcast LDS reads; mask matches permuted slot keys)
#pragma unroll
    for (int h2 = 0; h2 < 2; ++h2)
#pragma unroll
      for (int mt2 = 0; mt2 < 2; ++mt2)
#pragma unroll
        for (int r = 0; r < 4; ++r)
          S[h2][mt2][r] = S[h2][mt2][r]*0.125f
                        + smask[p*64 + h2*32 + q4*8 + mt2*4 + r];

    // ---- one online-softmax update over all 16 slots ----
    float tm = S[0][0][0];
#pragma unroll
    for (int h2 = 0; h2 < 2; ++h2)
#pragma unroll
      for (int mt2 = 0; mt2 < 2; ++mt2)
#pragma unroll
        for (int r = 0; r < 4; ++r) tm = fmaxf(tm, S[h2][mt2][r]);
    tm = fmaxf(tm, __shfl_xor(tm, 16));
    tm = fmaxf(tm, __shfl_xor(tm, 32));
    const float mn = fmaxf(m_i, tm);
    const float alpha = __expf(m_i - mn);
    m_i = mn;
#pragma unroll
    for (int h2 = 0; h2 < 2; ++h2)
#pragma unroll
      for (int mt2 = 0; mt2 < 2; ++mt2)
#pragma unroll
        for (int r = 0; r < 4; ++r)
          S[h2][mt2][r] = __expf(S[h2][mt2][r] - m_i);
    float rs = 0.f;
#pragma unroll
    for (int h2 = 0; h2 < 2; ++h2)
#pragma unroll
      for (int mt2 = 0; mt2 < 2; ++mt2)
#pragma unroll
        for (int r = 0; r < 4; ++r) rs += S[h2][mt2][r];
    rs += __shfl_xor(rs, 16);
    rs += __shfl_xor(rs, 32);
    l_i = l_i*alpha + rs;

    // rescale O once per phase (O row head = q4*4+r)
#pragma unroll
    for (int r = 0; r < 4; ++r) {
      const float ar = __shfl(alpha, q4*4 + r);
#pragma unroll
      for (int dt = 0; dt < 4; ++dt) Oa[dt][r] *= ar;
    }

    // ---- PV per 32-key half: P straight from S regs (zero shuffles) ----
#pragma unroll
    for (int h2 = 0; h2 < 2; ++h2) {
      float* const lV = stage + (g + h2)*ATTN_SLOT_F + 2048;
      bf16x8 vf[4];
#pragma unroll
      for (int dt = 0; dt < 4; ++dt) {
        union { bf16_t e[8]; bf16x8 v; } uv;
#pragma unroll
        for (int j = 0; j < 8; ++j) {
          const int row = q4*8 + j;
          const int fz = ((row & 7) << 2) ^ (((row >> 3) & 1) << 4);
          uv.e[j] = (bf16_t)lV[row*64 + ((dt*16 + c) ^ fz)];
        }
        vf[dt] = uv.v;
      }
      bf16x8 ph, pl;
      {
        union { bf16_t e[8]; bf16x8 v; } uh, ul;
#pragma unroll
        for (int j = 0; j < 8; ++j) {
          const float val = (j < 4) ? S[h2][0][j] : S[h2][1][j & 3];
          const bf16_t hi = (bf16_t)val;
          uh.e[j] = hi;
          ul.e[j] = (bf16_t)(val - (float)hi);
        }
        ph = uh.v;  pl = ul.v;
      }
      __builtin_amdgcn_s_setprio(1);
#pragma unroll
      for (int dt = 0; dt < 4; ++dt) {
        Oa[dt] = MFMA16(ph, vf[dt], Oa[dt]);
        Oa[dt] = MFMA16(pl, vf[dt], Oa[dt]);
      }
      __builtin_amdgcn_s_setprio(0);
    }
  }

  // ---- direct epilogue: this wave owns heads ht*16 .. ht*16+15 ----
  float* op = Op + ((long)u*NPB + pb)*NHc*HDc;
#pragma unroll
  for (int dt = 0; dt < 4; ++dt)
#pragma unroll
    for (int r = 0; r < 4; ++r) {
      const int h = ht*16 + q4*4 + r;
      if (h < NHc) op[h*HDc + dt*16 + c] = Oa[dt][r];
    }
  if (q4 == 0) {
    const int hh = ht*16 + c;
    if (hh < NHc) {
      Mp[((long)u*NPB + pb)*NHc + hh] = fmaxf(m_i, -1e30f);
      Lp[((long)u*NPB + pb)*NHc + hh] = l_i;
    }
  }
}

// ---------------- Kernel 4: combine + current token, grid (71,32) ----------------
__global__ __launch_bounds__(64) void k_combine(
    const float* __restrict__ Mp, const float* __restrict__ Lp,
    const float* __restrict__ Op,
    const bf16_t* __restrict__ qhi, const bf16_t* __restrict__ qlo,
    const float* __restrict__ kcur, const float* __restrict__ vcur,
    bf16_t* __restrict__ ahi, bf16_t* __restrict__ alo, const int NPB)
{
  const int h = blockIdx.x, u = blockIdx.y;
  const int lane = threadIdx.x;   // = d
  const long qidx = ((long)u*NHPc + h)*HDc + lane;
  float pr = ((float)qhi[qidx] + (float)qlo[qidx]) * kcur[u*HDc + lane];
#pragma unroll
  for (int o = 32; o > 0; o >>= 1) pr += __shfl_xor(pr, o);
  const float s_cur = pr * 0.125f;

  float g = s_cur;
  for (int p = 0; p < NPB; ++p)
    g = fmaxf(g, Mp[((long)u*NPB + p)*NHc + h]);
  g = fmaxf(g, -1e30f);
  float sw = 0.f, acc = 0.f;
  const float* ob = Op + (long)u*NPB*NHc*HDc + (long)h*HDc + lane;
  for (int p = 0; p < NPB; ++p) {
    const float f = __expf(Mp[((long)u*NPB + p)*NHc + h] - g);
    sw += f*Lp[((long)u*NPB + p)*NHc + h];
    acc += f*ob[(long)p*NHc*HDc];
  }
  const float cw = __expf(s_cur - g);
  acc += cw * vcur[u*HDc + lane];
  const float attn = acc / (sw + cw);
  const bf16_t hi = (bf16_t)attn;
  ahi[(long)u*HIDc + h*HDc + lane] = hi;
  alo[(long)u*HIDc + h*HDc + lane] = (bf16_t)(attn - (float)hi);
}

// ---------------- Kernel 5: dense GEMM, grid (142,8), atomic reduce ----------------
__global__ __launch_bounds__(256) void k_outgemm(
    const bf16_t* __restrict__ ahi, const bf16_t* __restrict__ alo,
    const float* __restrict__ wd, float* __restrict__ out)
{
  const int nb = blockIdx.x, y = blockIdx.y;
  const int t = threadIdx.x;
  const int wave = t >> 6, lane = t & 63;
  const int c = lane & 15, q4 = lane >> 4;
  const int mt = wave & 1, kh = wave >> 1;
  const int ks0 = y*18;
  const int ksn = min(18, 142 - ks0);
  const int h1  = ksn >> 1;
  const int kbeg = ks0 + (kh ? h1 : 0);
  const int kend = ks0 + (kh ? ksn : h1);
  __shared__ float sC[Uc*32];

  const bf16_t* aph = ahi + ((long)(mt*16 + c))*HIDc + q4*8;
  const bf16_t* apl = alo + ((long)(mt*16 + c))*HIDc + q4*8;
  const long bbase = ((long)nb*32 + c)*HIDc + q4*8;

  f32x4 acc[2] = {};
#pragma unroll 3
  for (int ks = kbeg; ks < kend; ++ks) {
    const bf16x8 Ah = *(const bf16x8*)(aph + ks*32);
    const bf16x8 Al = *(const bf16x8*)(apl + ks*32);
#pragma unroll
    for (int nf = 0; nf < 2; ++nf) {
      const bf16x8 B = ld8f(wd, bbase + (long)nf*16*HIDc + ks*32);
      acc[nf] = MFMA16(Ah, B, acc[nf]);
      acc[nf] = MFMA16(Al, B, acc[nf]);
    }
  }
  if (kh == 0) {
#pragma unroll
    for (int r = 0; r < 4; ++r)
#pragma unroll
      for (int nf = 0; nf < 2; ++nf)
        sC[(mt*16 + q4*4 + r)*32 + nf*16 + c] = acc[nf][r];
  }
  __syncthreads();
  if (kh == 1) {
#pragma unroll
    for (int r = 0; r < 4; ++r)
#pragma unroll
      for (int nf = 0; nf < 2; ++nf)
        sC[(mt*16 + q4*4 + r)*32 + nf*16 + c] += acc[nf][r];
  }
  __syncthreads();
  for (int i = t; i < Uc*32; i += 256)
    atomicAdd(&out[(long)(i >> 5)*HIDc + nb*32 + (i & 31)], sC[i]);
}

extern "C" void kernel_launch(void* const* d_in, const int* in_sizes, int n_in,
                              void* d_out, int out_size, void* d_ws, size_t ws_size,
                              hipStream_t stream)
{
  const float* hidden = (const float*)d_in[0];
  const float* cosp   = (const float*)d_in[1];
  const float* sinp   = (const float*)d_in[2];
  const float* kcache = (const float*)d_in[3];
  const float* vcache = (const float*)d_in[4];
  const float* masks  = (const float*)d_in[5];
  const float* wqkv   = (const float*)d_in[6];
  const float* wdense = (const float*)d_in[7];
  float* out = (float*)d_out;

  // pick NPB (flash partials per user) by available workspace
  const size_t opb = (size_t)Uc*NHc*HDc*4;
  int NPB = 16;
  if      (ws_size >= OFF_OP + 16*opb) NPB = 16;
  else if (ws_size >= OFF_OP +  8*opb) NPB = 8;
  else if (ws_size >= OFF_OP +  4*opb) NPB = 4;
  else return;

  char* ws = (char*)d_ws;
  float*  fused = (float*)(ws + OFF_FUSED);
  bf16_t* qhi   = (bf16_t*)(ws + OFF_QHI);
  bf16_t* qlo   = (bf16_t*)(ws + OFF_QLO);
  float*  kcur  = (float*)(ws + OFF_KCUR);
  float*  vcur  = (float*)(ws + OFF_VCUR);
  float*  Mp    = (float*)(ws + OFF_MP);
  float*  Lp    = (float*)(ws + OFF_LP);
  bf16_t* ahi   = (bf16_t*)(ws + OFF_AHI);
  bf16_t* alo   = (bf16_t*)(ws + OFF_ALO);
  float*  Op    = (float*)(ws + OFF_OP);

  // allow >64KB dynamic LDS for k_attn (gfx950: 160KB/CU, 2 blocks/CU here)
  hipFuncSetAttribute(reinterpret_cast<const void*>(k_attn),
                      hipFuncAttributeMaxDynamicSharedMemorySize, ATTN_SMEM_BYTES);

  k_zeros  <<<1152, 256, 0, stream>>>(fused, out);
  k_qkv    <<<dim3(73, 8), 256, 0, stream>>>(hidden, wqkv, fused);
  k_rotary <<<dim3(80, 4), 256, 0, stream>>>(fused, cosp, sinp, qhi, qlo, kcur, vcur);
  k_attn   <<<dim3(32, NPB), 512, ATTN_SMEM_BYTES, stream>>>(kcache, vcache, masks, qhi, qlo, Mp, Lp, Op, NPB);
  k_combine<<<dim3(71, 32), 64, 0, stream>>>(Mp, Lp, Op, qhi, qlo, kcur, vcur, ahi, alo, NPB);
  k_outgemm<<<dim3(142, 8), 256, 0, stream>>>(ahi, alo, wdense, out);
}

// Round 4
// 324.993 us; speedup vs baseline: 1.0394x; 1.0394x over previous
//
#include <hip/hip_runtime.h>
#include <hip/hip_bf16.h>

typedef __bf16 bf16_t;
typedef __bf16 bf16x8 __attribute__((ext_vector_type(8)));
typedef float  f32x4  __attribute__((ext_vector_type(4)));

#define MFMA16(A,B,C) __builtin_amdgcn_mfma_f32_16x16x32_bf16(A,B,C,0,0,0)

constexpr int HIDc = 4544;   // 142 k-steps of 32
constexpr int NHc  = 71;
constexpr int NHPc = 80;
constexpr int HDc  = 64;
constexpr int Uc   = 32;
constexpr int Sc   = 2048;
constexpr int RQ   = 4672;   // (71+2)*64

// ---- workspace layout (bytes) ----
constexpr size_t OFF_FUSED = 0;           // [32][4672] f32 = 598016
constexpr size_t OFF_QHI   = 598016;      // [32][80][64] bf16
constexpr size_t OFF_QLO   = 925696;
constexpr size_t OFF_KCUR  = 1253376;     // [32][64] f32
constexpr size_t OFF_VCUR  = 1261568;
constexpr size_t OFF_MP    = 1269760;     // [32][NPB<=16][71] f32 (max 145408)
constexpr size_t OFF_LP    = 1415168;
constexpr size_t OFF_AHI   = 1560576;     // [32][4544] bf16
constexpr size_t OFF_ALO   = 1851392;
constexpr size_t OFF_OP    = 2142208;     // [32][NPB][71][64] f32

// fp32 -> bf16x8 load (32B aligned)
__device__ __forceinline__ bf16x8 ld8f(const float* base, long eidx) {
  const float* p = base + eidx;
  const f32x4 a = *(const f32x4*)p;
  const f32x4 b = *(const f32x4*)(p + 4);
  bf16x8 r;
  r[0]=(bf16_t)a[0]; r[1]=(bf16_t)a[1]; r[2]=(bf16_t)a[2]; r[3]=(bf16_t)a[3];
  r[4]=(bf16_t)b[0]; r[5]=(bf16_t)b[1]; r[6]=(bf16_t)b[2]; r[7]=(bf16_t)b[3];
  return r;
}

// async global -> LDS copies (lds dest = wave-uniform base + lane*size)
__device__ __forceinline__ void cp16(const float* g, float* l) {
  __builtin_amdgcn_global_load_lds((const __attribute__((address_space(1))) void*)g,
                                   (__attribute__((address_space(3))) void*)l, 16, 0, 0);
}
__device__ __forceinline__ void cp4(const float* g, float* l) {
  __builtin_amdgcn_global_load_lds((const __attribute__((address_space(1))) void*)g,
                                   (__attribute__((address_space(3))) void*)l, 4, 0, 0);
}

// ---------------- zero fused + d_out ----------------
__global__ __launch_bounds__(256) void k_zeros(float* fused, float* out) {
  const int i = blockIdx.x*256 + threadIdx.x;       // grid 1152 -> 294912
  if (i < Uc*RQ) fused[i] = 0.f;
  else           out[i - Uc*RQ] = 0.f;              // Uc*HIDc elements
}

// ---------------- Kernel 1: QKV GEMM, grid (73,16), atomic reduce ----------------
__global__ __launch_bounds__(256) void k_qkv(
    const float* __restrict__ hidden, const float* __restrict__ wqkv,
    float* __restrict__ fused)
{
  const int h = blockIdx.x, y = blockIdx.y;
  const int t = threadIdx.x;
  const int wave = t >> 6, lane = t & 63;
  const int c = lane & 15, q4 = lane >> 4;
  const int mt = wave & 1, kh = wave >> 1;
  const int ks0 = y*9;
  const int ksn = min(9, 142 - ks0);      // y=15 gets 7
  const int h1  = ksn >> 1;
  const int kbeg = ks0 + (kh ? h1 : 0);
  const int kend = ks0 + (kh ? ksn : h1);
  __shared__ float sD[Uc*HDc];

  const long abase = (long)(mt*16 + c)*HIDc + q4*8;
  const long bbase = ((long)h*64 + c)*HIDc + q4*8;
  f32x4 acc[4] = {};
#pragma unroll 3
  for (int ks = kbeg; ks < kend; ++ks) {
    const bf16x8 af = ld8f(hidden, abase + ks*32);
#pragma unroll
    for (int nf = 0; nf < 4; ++nf) {
      const bf16x8 bv = ld8f(wqkv, bbase + (long)nf*16*HIDc + ks*32);
      acc[nf] = MFMA16(af, bv, acc[nf]);
    }
  }
  if (kh == 0) {
#pragma unroll
    for (int r = 0; r < 4; ++r)
#pragma unroll
      for (int nf = 0; nf < 4; ++nf)
        sD[(mt*16 + q4*4 + r)*64 + nf*16 + c] = acc[nf][r];
  }
  __syncthreads();
  if (kh == 1) {
#pragma unroll
    for (int r = 0; r < 4; ++r)
#pragma unroll
      for (int nf = 0; nf < 4; ++nf)
        sD[(mt*16 + q4*4 + r)*64 + nf*16 + c] += acc[nf][r];
  }
  __syncthreads();
  for (int i = t; i < Uc*HDc; i += 256)
    atomicAdd(&fused[(long)(i >> 6)*RQ + h*64 + (i & 63)], sD[i]);
}

// ---------------- Kernel 2: rotary + hi/lo split, grid (80,4) ----------------
__global__ __launch_bounds__(256) void k_rotary(
    const float* __restrict__ fused,
    const float* __restrict__ cosp, const float* __restrict__ sinp,
    bf16_t* __restrict__ qhi, bf16_t* __restrict__ qlo,
    float* __restrict__ kcur, float* __restrict__ vcur)
{
  const int h  = blockIdx.x;    // 0..79
  const int u0 = blockIdx.y*8;  // 8 users per block
  const int t = threadIdx.x;
  __shared__ float sD[8*HDc];
  if (h < 73) {
    for (int i = t; i < 8*HDc; i += 256)
      sD[i] = fused[(long)(u0 + (i >> 6))*RQ + h*64 + (i & 63)];
    __syncthreads();
  }
  if (h >= NHc) {  // zero q pad rows 71..79
    for (int i = t; i < 8*HDc; i += 256) {
      const long idx = (((long)(u0 + (i >> 6)))*NHPc + h)*HDc + (i & 63);
      qhi[idx] = (bf16_t)0.f;  qlo[idx] = (bf16_t)0.f;
    }
  }
  if (h >= 73) return;
  for (int i = t; i < 8*HDc; i += 256) {
    const int u = u0 + (i >> 6), d = i & 63;
    const float x = sD[i];
    const float partner = sD[i ^ 32];     // flips d bit 5 only (same u)
    const float cs = cosp[u*HDc + d];
    const float sn = sinp[u*HDc + d];
    const float rh = (d < 32) ? -partner : partner;
    const float val = x*cs + rh*sn;
    if (h < NHc) {
      const long idx = ((long)u*NHPc + h)*HDc + d;
      const bf16_t hi = (bf16_t)val;
      qhi[idx] = hi;
      qlo[idx] = (bf16_t)(val - (float)hi);
    } else if (h == NHc) {
      kcur[u*HDc + d] = val;     // rotated shared K head
    } else {
      vcur[u*HDc + d] = x;       // V head: no rotary
    }
  }
}

// ---------------- Kernel 3: flash-decode partials, grid (32, NPB) ----------------
// Cooperative producer/consumer block: 8 waves (512 thr), 1 block/CU.
//   waves 0-4 : consumers, wave = head-tile ht (16 heads each, NHP=80)
//   wave 5    : K producer     wave 6 : V producer    wave 7 : mask producer
// DEEP RING: 4 x 64-key groups; prefetch distance 3 phases (~6k cy latency
// cover). Group layout (floats): g*8192 + [K: sl*2048 x2 | V: 4096 + sl*2048].
// Producer per phase p: B1 (group (p+3)&3 vacated) -> issue 16 cp16 for
// phase p+3 -> s_waitcnt vmcnt(48) (phase p landed; p+1..p+3 = 48 in flight)
// -> B2 (phase p ready). Consumers: 2x __syncthreads then compute 64 keys.
constexpr int ATTN_GRP_F    = 8192;                     // one 64-key group
constexpr int ATTN_RING     = 4;
constexpr int ATTN_STAGE_F  = ATTN_RING*ATTN_GRP_F;     // 32768
constexpr int ATTN_SMEM_F   = ATTN_STAGE_F + 2048;      // + masks (<=2048 f)
constexpr int ATTN_SMEM_BYTES = ATTN_SMEM_F * 4;        // 139264 -> 1 block/CU

__global__ __launch_bounds__(512, 2) void k_attn(
    const float* __restrict__ kc, const float* __restrict__ vc,
    const float* __restrict__ masks,
    const bf16_t* __restrict__ qhi, const bf16_t* __restrict__ qlo,
    float* __restrict__ Mp, float* __restrict__ Lp, float* __restrict__ Op,
    const int NPB)
{
  extern __shared__ float smem[];
  const int u  = blockIdx.x;
  const int pb = blockIdx.y;
  const int tid = threadIdx.x;
  const int wave = __builtin_amdgcn_readfirstlane(tid >> 6);
  const int lane = tid & 63;
  const int c    = lane & 15;
  const int q4   = lane >> 4;
  const int pbpc = NPB >> 2;            // partial blocks per chunk
  const int keys_pb = 2048 / pbpc;      // keys per block
  const int ph_cnt  = keys_pb >> 6;     // 64-key phases (>=8)
  const int chunk = pb / pbpc;
  const int inner = pb - chunk*pbpc;
  const int s_base = inner*keys_pb;
  const long kvbase = ((long)(chunk*Uc + u))*Sc;

  float* const stage = smem;
  float* const smask = smem + ATTN_STAGE_F;

  const int srow = lane >> 4;           // dest row within 4-row group
  const int scol = (lane & 15) << 2;    // dest d' base (f32 words)

  if (wave >= 5) {
    // ================= producer path =================
    if (wave == 7) {
      const int nmc = keys_pb >> 6;
      const float* gM = masks + kvbase + s_base;
      for (int i = 0; i < nmc; ++i)
        cp4(gM + i*64 + lane, smask + i*64);
      for (int p = 0; p < ph_cnt; ++p) {
        __builtin_amdgcn_s_barrier();                       // B1
        if (p == 0) asm volatile("s_waitcnt vmcnt(0)" ::: "memory");
        __builtin_amdgcn_s_barrier();                       // B2
      }
      return;
    }
    const float* gsrc = (wave == 5) ? kc : vc;
    const int vofs = (wave == 6) ? 4096 : 0;
    // prologue: phases 0..2 -> groups 0..2 (48 cp16)
#pragma unroll
    for (int pt = 0; pt < 3; ++pt) {
#pragma unroll
      for (int sl = 0; sl < 2; ++sl) {
        const long tb = (kvbase + s_base + pt*64 + sl*32) * 64;
        float* dst = stage + pt*ATTN_GRP_F + vofs + sl*2048;
#pragma unroll
        for (int i = 0; i < 8; ++i) {
          const int row = i*4 + srow;
          const int fz = ((row & 7) << 2) ^ (((row >> 3) & 1) << 4);
          cp16(gsrc + tb + row*64 + (scol ^ fz), dst + i*256);
        }
      }
    }
    for (int p = 0; p < ph_cnt; ++p) {
      __builtin_amdgcn_s_barrier();                         // B1: group (p+3)&3 free
      if (p + 3 < ph_cnt) {
        const int g = (p+3) & 3;
#pragma unroll
        for (int sl = 0; sl < 2; ++sl) {
          const long tb = (kvbase + s_base + (long)(p+3)*64 + sl*32) * 64;
          float* dst = stage + g*ATTN_GRP_F + vofs + sl*2048;
#pragma unroll
          for (int i = 0; i < 8; ++i) {
            const int row = i*4 + srow;
            const int fz = ((row & 7) << 2) ^ (((row >> 3) & 1) << 4);
            cp16(gsrc + tb + row*64 + (scol ^ fz), dst + i*256);
          }
        }
      }
      const int rem = min(3, ph_cnt - 1 - p);   // phases still in flight after wait
      if      (rem >= 3) asm volatile("s_waitcnt vmcnt(48)" ::: "memory");
      else if (rem == 2) asm volatile("s_waitcnt vmcnt(32)" ::: "memory");
      else if (rem == 1) asm volatile("s_waitcnt vmcnt(16)" ::: "memory");
      else               asm volatile("s_waitcnt vmcnt(0)"  ::: "memory");
      __builtin_amdgcn_s_barrier();                         // B2: phase p ready
    }
    return;
  }

  // ================= consumer path (wave = ht, 16 heads) =================
  const int ht = wave;
  bf16x8 qh[2], ql[2];
  {
    const bf16_t* qb  = qhi + ((long)u*NHPc + ht*16 + c)*HDc + q4*8;
    const bf16_t* qb2 = qlo + ((long)u*NHPc + ht*16 + c)*HDc + q4*8;
#pragma unroll
    for (int ks = 0; ks < 2; ++ks) {
      qh[ks] = *(const bf16x8*)(qb  + ks*32);
      ql[ks] = *(const bf16x8*)(qb2 + ks*32);
    }
  }

  float m_i = -INFINITY, l_i = 0.f;
  f32x4 Oa[4] = {};

  // K-row permutation so S^T C-layout == PV A-layout (zero shuffles):
  // A row m=c reads key(in 32-slot) = krow0 + mt2*4, krow0 = (c>>2)*8 + (c&3)
  const int krow0 = ((c >> 2) << 3) + (c & 3);

  for (int p = 0; p < ph_cnt; ++p) {
    __syncthreads();                                        // B1
    __syncthreads();                                        // B2: phase p ready
    float* const grp = stage + (p & 3)*ATTN_GRP_F;

    // ---- QK: 4 subtiles (h2, mt2); key = h2*32 + q4*8 + mt2*4 + r ----
    f32x4 S[2][2];
    __builtin_amdgcn_s_setprio(1);
#pragma unroll
    for (int h2 = 0; h2 < 2; ++h2) {
      float* const lK = grp + h2*2048;
#pragma unroll
      for (int mt2 = 0; mt2 < 2; ++mt2) {
        const int row = krow0 + mt2*4;
        const int fz = ((row & 7) << 2) ^ (((row >> 3) & 1) << 4);
        bf16x8 k0, k1;
#pragma unroll
        for (int ks = 0; ks < 2; ++ks) {
          const int b0 = row*64 + ((ks*32 + q4*8) ^ fz);
          const int b1 = row*64 + ((ks*32 + q4*8 + 4) ^ fz);
          const f32x4 a = *(const f32x4*)(lK + b0);
          const f32x4 b = *(const f32x4*)(lK + b1);
          bf16x8 r;
          r[0]=(bf16_t)a[0]; r[1]=(bf16_t)a[1]; r[2]=(bf16_t)a[2]; r[3]=(bf16_t)a[3];
          r[4]=(bf16_t)b[0]; r[5]=(bf16_t)b[1]; r[6]=(bf16_t)b[2]; r[7]=(bf16_t)b[3];
          if (ks == 0) k0 = r; else k1 = r;
        }
        f32x4 s = {};
        s = MFMA16(k0, qh[0], s);
        s = MFMA16(k1, qh[1], s);
        s = MFMA16(k0, ql[0], s);
        s = MFMA16(k1, ql[1], s);
        S[h2][mt2] = s;
      }
    }
    __builtin_amdgcn_s_setprio(0);

    // scale + mask (broadcast LDS reads; mask matches permuted slot keys)
#pragma unroll
    for (int h2 = 0; h2 < 2; ++h2)
#pragma unroll
      for (int mt2 = 0; mt2 < 2; ++mt2)
#pragma unroll
        for (int r = 0; r < 4; ++r)
          S[h2][mt2][r] = S[h2][mt2][r]*0.125f
                        + smask[p*64 + h2*32 + q4*8 + mt2*4 + r];

    // ---- one online-softmax update over all 16 slots ----
    float tm = S[0][0][0];
#pragma unroll
    for (int h2 = 0; h2 < 2; ++h2)
#pragma unroll
      for (int mt2 = 0; mt2 < 2; ++mt2)
#pragma unroll
        for (int r = 0; r < 4; ++r) tm = fmaxf(tm, S[h2][mt2][r]);
    tm = fmaxf(tm, __shfl_xor(tm, 16));
    tm = fmaxf(tm, __shfl_xor(tm, 32));
    const float mn = fmaxf(m_i, tm);
    const float alpha = __expf(m_i - mn);
    m_i = mn;
#pragma unroll
    for (int h2 = 0; h2 < 2; ++h2)
#pragma unroll
      for (int mt2 = 0; mt2 < 2; ++mt2)
#pragma unroll
        for (int r = 0; r < 4; ++r)
          S[h2][mt2][r] = __expf(S[h2][mt2][r] - m_i);
    float rs = 0.f;
#pragma unroll
    for (int h2 = 0; h2 < 2; ++h2)
#pragma unroll
      for (int mt2 = 0; mt2 < 2; ++mt2)
#pragma unroll
        for (int r = 0; r < 4; ++r) rs += S[h2][mt2][r];
    rs += __shfl_xor(rs, 16);
    rs += __shfl_xor(rs, 32);
    l_i = l_i*alpha + rs;

    // rescale O once per phase (O row head = q4*4+r)
#pragma unroll
    for (int r = 0; r < 4; ++r) {
      const float ar = __shfl(alpha, q4*4 + r);
#pragma unroll
      for (int dt = 0; dt < 4; ++dt) Oa[dt][r] *= ar;
    }

    // ---- PV per 32-key half: P straight from S regs (zero shuffles) ----
#pragma unroll
    for (int h2 = 0; h2 < 2; ++h2) {
      float* const lV = grp + 4096 + h2*2048;
      bf16x8 vf[4];
#pragma unroll
      for (int dt = 0; dt < 4; ++dt) {
        union { bf16_t e[8]; bf16x8 v; } uv;
#pragma unroll
        for (int j = 0; j < 8; ++j) {
          const int row = q4*8 + j;
          const int fz = ((row & 7) << 2) ^ (((row >> 3) & 1) << 4);
          uv.e[j] = (bf16_t)lV[row*64 + ((dt*16 + c) ^ fz)];
        }
        vf[dt] = uv.v;
      }
      bf16x8 ph, pl;
      {
        union { bf16_t e[8]; bf16x8 v; } uh, ul;
#pragma unroll
        for (int j = 0; j < 8; ++j) {
          const float val = (j < 4) ? S[h2][0][j] : S[h2][1][j & 3];
          const bf16_t hi = (bf16_t)val;
          uh.e[j] = hi;
          ul.e[j] = (bf16_t)(val - (float)hi);
        }
        ph = uh.v;  pl = ul.v;
      }
      __builtin_amdgcn_s_setprio(1);
#pragma unroll
      for (int dt = 0; dt < 4; ++dt) {
        Oa[dt] = MFMA16(ph, vf[dt], Oa[dt]);
        Oa[dt] = MFMA16(pl, vf[dt], Oa[dt]);
      }
      __builtin_amdgcn_s_setprio(0);
    }
  }

  // ---- direct epilogue: this wave owns heads ht*16 .. ht*16+15 ----
  float* op = Op + ((long)u*NPB + pb)*NHc*HDc;
#pragma unroll
  for (int dt = 0; dt < 4; ++dt)
#pragma unroll
    for (int r = 0; r < 4; ++r) {
      const int h = ht*16 + q4*4 + r;
      if (h < NHc) op[h*HDc + dt*16 + c] = Oa[dt][r];
    }
  if (q4 == 0) {
    const int hh = ht*16 + c;
    if (hh < NHc) {
      Mp[((long)u*NPB + pb)*NHc + hh] = fmaxf(m_i, -1e30f);
      Lp[((long)u*NPB + pb)*NHc + hh] = l_i;
    }
  }
}

// ---------------- Kernel 4: combine + current token, grid (71,32) ----------------
__global__ __launch_bounds__(64) void k_combine(
    const float* __restrict__ Mp, const float* __restrict__ Lp,
    const float* __restrict__ Op,
    const bf16_t* __restrict__ qhi, const bf16_t* __restrict__ qlo,
    const float* __restrict__ kcur, const float* __restrict__ vcur,
    bf16_t* __restrict__ ahi, bf16_t* __restrict__ alo, const int NPB)
{
  const int h = blockIdx.x, u = blockIdx.y;
  const int lane = threadIdx.x;   // = d
  const long qidx = ((long)u*NHPc + h)*HDc + lane;
  float pr = ((float)qhi[qidx] + (float)qlo[qidx]) * kcur[u*HDc + lane];
#pragma unroll
  for (int o = 32; o > 0; o >>= 1) pr += __shfl_xor(pr, o);
  const float s_cur = pr * 0.125f;

  float g = s_cur;
  for (int p = 0; p < NPB; ++p)
    g = fmaxf(g, Mp[((long)u*NPB + p)*NHc + h]);
  g = fmaxf(g, -1e30f);
  float sw = 0.f, acc = 0.f;
  const float* ob = Op + (long)u*NPB*NHc*HDc + (long)h*HDc + lane;
  for (int p = 0; p < NPB; ++p) {
    const float f = __expf(Mp[((long)u*NPB + p)*NHc + h] - g);
    sw += f*Lp[((long)u*NPB + p)*NHc + h];
    acc += f*ob[(long)p*NHc*HDc];
  }
  const float cw = __expf(s_cur - g);
  acc += cw * vcur[u*HDc + lane];
  const float attn = acc / (sw + cw);
  const bf16_t hi = (bf16_t)attn;
  ahi[(long)u*HIDc + h*HDc + lane] = hi;
  alo[(long)u*HIDc + h*HDc + lane] = (bf16_t)(attn - (float)hi);
}

// ---------------- Kernel 5: dense GEMM, grid (142,16), atomic reduce ----------------
__global__ __launch_bounds__(256) void k_outgemm(
    const bf16_t* __restrict__ ahi, const bf16_t* __restrict__ alo,
    const float* __restrict__ wd, float* __restrict__ out)
{
  const int nb = blockIdx.x, y = blockIdx.y;
  const int t = threadIdx.x;
  const int wave = t >> 6, lane = t & 63;
  const int c = lane & 15, q4 = lane >> 4;
  const int mt = wave & 1, kh = wave >> 1;
  const int ks0 = y*9;
  const int ksn = min(9, 142 - ks0);
  const int h1  = ksn >> 1;
  const int kbeg = ks0 + (kh ? h1 : 0);
  const int kend = ks0 + (kh ? ksn : h1);
  __shared__ float sC[Uc*32];

  const bf16_t* aph = ahi + ((long)(mt*16 + c))*HIDc + q4*8;
  const bf16_t* apl = alo + ((long)(mt*16 + c))*HIDc + q4*8;
  const long bbase = ((long)nb*32 + c)*HIDc + q4*8;

  f32x4 acc[2] = {};
#pragma unroll 3
  for (int ks = kbeg; ks < kend; ++ks) {
    const bf16x8 Ah = *(const bf16x8*)(aph + ks*32);
    const bf16x8 Al = *(const bf16x8*)(apl + ks*32);
#pragma unroll
    for (int nf = 0; nf < 2; ++nf) {
      const bf16x8 B = ld8f(wd, bbase + (long)nf*16*HIDc + ks*32);
      acc[nf] = MFMA16(Ah, B, acc[nf]);
      acc[nf] = MFMA16(Al, B, acc[nf]);
    }
  }
  if (kh == 0) {
#pragma unroll
    for (int r = 0; r < 4; ++r)
#pragma unroll
      for (int nf = 0; nf < 2; ++nf)
        sC[(mt*16 + q4*4 + r)*32 + nf*16 + c] = acc[nf][r];
  }
  __syncthreads();
  if (kh == 1) {
#pragma unroll
    for (int r = 0; r < 4; ++r)
#pragma unroll
      for (int nf = 0; nf < 2; ++nf)
        sC[(mt*16 + q4*4 + r)*32 + nf*16 + c] += acc[nf][r];
  }
  __syncthreads();
  for (int i = t; i < Uc*32; i += 256)
    atomicAdd(&out[(long)(i >> 5)*HIDc + nb*32 + (i & 31)], sC[i]);
}

extern "C" void kernel_launch(void* const* d_in, const int* in_sizes, int n_in,
                              void* d_out, int out_size, void* d_ws, size_t ws_size,
                              hipStream_t stream)
{
  const float* hidden = (const float*)d_in[0];
  const float* cosp   = (const float*)d_in[1];
  const float* sinp   = (const float*)d_in[2];
  const float* kcache = (const float*)d_in[3];
  const float* vcache = (const float*)d_in[4];
  const float* masks  = (const float*)d_in[5];
  const float* wqkv   = (const float*)d_in[6];
  const float* wdense = (const float*)d_in[7];
  float* out = (float*)d_out;

  // NPB=8 -> grid 32x8 = 256 blocks = exactly 1 per CU (deep-ring config)
  const size_t opb = (size_t)Uc*NHc*HDc*4;
  int NPB = 8;
  if      (ws_size >= OFF_OP + 8*opb) NPB = 8;
  else if (ws_size >= OFF_OP + 4*opb) NPB = 4;
  else return;

  char* ws = (char*)d_ws;
  float*  fused = (float*)(ws + OFF_FUSED);
  bf16_t* qhi   = (bf16_t*)(ws + OFF_QHI);
  bf16_t* qlo   = (bf16_t*)(ws + OFF_QLO);
  float*  kcur  = (float*)(ws + OFF_KCUR);
  float*  vcur  = (float*)(ws + OFF_VCUR);
  float*  Mp    = (float*)(ws + OFF_MP);
  float*  Lp    = (float*)(ws + OFF_LP);
  bf16_t* ahi   = (bf16_t*)(ws + OFF_AHI);
  bf16_t* alo   = (bf16_t*)(ws + OFF_ALO);
  float*  Op    = (float*)(ws + OFF_OP);

  // allow >64KB dynamic LDS for k_attn (gfx950: 160KB/CU, 1 block/CU here)
  hipFuncSetAttribute(reinterpret_cast<const void*>(k_attn),
                      hipFuncAttributeMaxDynamicSharedMemorySize, ATTN_SMEM_BYTES);

  k_zeros  <<<1152, 256, 0, stream>>>(fused, out);
  k_qkv    <<<dim3(73, 16), 256, 0, stream>>>(hidden, wqkv, fused);
  k_rotary <<<dim3(80, 4), 256, 0, stream>>>(fused, cosp, sinp, qhi, qlo, kcur, vcur);
  k_attn   <<<dim3(32, NPB), 512, ATTN_SMEM_BYTES, stream>>>(kcache, vcache, masks, qhi, qlo, Mp, Lp, Op, NPB);
  k_combine<<<dim3(71, 32), 64, 0, stream>>>(Mp, Lp, Op, qhi, qlo, kcur, vcur, ahi, alo, NPB);
  k_outgemm<<<dim3(142, 16), 256, 0, stream>>>(ahi, alo, wdense, out);
}